// Round 1
// baseline (1164.750 us; speedup 1.0000x reference)
//
#include <hip/hip_runtime.h>
#include <math.h>

#define NN 4096
#define CC 64
#define C8 8
#define NB 4

// ---------------------------------------------------------------------------
// K1a: q,k projections.  qrec[b][n][16] = {q0..q7, (rowmax later), pad...}
//      kpack[b][m][8]
// ---------------------------------------------------------------------------
__global__ void proj_qk(const float* __restrict__ x,
                        const float* __restrict__ wq, const float* __restrict__ bq,
                        const float* __restrict__ wk, const float* __restrict__ bk,
                        float* __restrict__ qrec, float* __restrict__ kpack) {
    int gid = blockIdx.x * 256 + threadIdx.x;   // 0..16383 == b*4096+n
    int b = gid >> 12;
    int n = gid & 4095;
    const float* xp = x + ((size_t)b * CC) * NN + n;
    float xr[CC];
#pragma unroll
    for (int c = 0; c < CC; ++c) xr[c] = xp[(size_t)c * NN];

    float aq[C8], ak[C8];
#pragma unroll
    for (int o = 0; o < C8; ++o) {
        float sq = 0.f, sk = 0.f;
#pragma unroll
        for (int c = 0; c < CC; ++c) {
            sq = fmaf(wq[o * CC + c], xr[c], sq);
            sk = fmaf(wk[o * CC + c], xr[c], sk);
        }
        aq[o] = sq + bq[o];
        ak[o] = sk + bk[o];
    }
    float* qr = qrec + ((size_t)gid) * 16;
#pragma unroll
    for (int o = 0; o < C8; ++o) qr[o] = aq[o];
    float* kr = kpack + ((size_t)gid) * 8;
#pragma unroll
    for (int o = 0; o < C8; ++o) kr[o] = ak[o];
}

// ---------------------------------------------------------------------------
// K1b: v projection.  vpack[b][n][c]  (n-major so a 16-float c-slice is
// contiguous -> wave-uniform s_load in attn_pv)
// ---------------------------------------------------------------------------
__global__ void proj_v(const float* __restrict__ x,
                       const float* __restrict__ wv, const float* __restrict__ bv,
                       float* __restrict__ vpack) {
    int cgu = __builtin_amdgcn_readfirstlane((int)(threadIdx.x >> 6));
    int bn = blockIdx.x * 64 + (threadIdx.x & 63);   // b*4096+n
    int b = bn >> 12;
    const float* xp = x + ((size_t)b * CC) * NN + (bn & 4095);
    float xr[CC];
#pragma unroll
    for (int c = 0; c < CC; ++c) xr[c] = xp[(size_t)c * NN];

    float acc[16];
#pragma unroll
    for (int i = 0; i < 16; ++i) {
        int co = cgu * 16 + i;
        float s = 0.f;
#pragma unroll
        for (int c = 0; c < CC; ++c) s = fmaf(wv[co * CC + c], xr[c], s);
        acc[i] = s + bv[co];
    }
    float* vp = vpack + ((size_t)bn) * CC + cgu * 16;
#pragma unroll
    for (int i = 0; i < 16; ++i) vp[i] = acc[i];
}

// ---------------------------------------------------------------------------
// K2: per-row online max/sumexp over an m-eighth.  lane <-> row n,
// k record is wave-uniform -> scalar loads.  pmax/psum: [b][split][n]
// ---------------------------------------------------------------------------
__global__ void row_stats(const float* __restrict__ qrec,
                          const float* __restrict__ kpack,
                          float* __restrict__ pmax, float* __restrict__ psum) {
    int w = __builtin_amdgcn_readfirstlane((int)(blockIdx.x * 4) + (int)(threadIdx.x >> 6));
    int lane = threadIdx.x & 63;
    int b = w >> 9;            // 512 waves per batch
    int sp = (w >> 6) & 7;     // m-split 0..7
    int chunk = w & 63;
    int n = chunk * 64 + lane;

    const float* qr = qrec + ((size_t)(b * NN + n)) * 16;
    float q[C8];
#pragma unroll
    for (int o = 0; o < C8; ++o) q[o] = qr[o];

    float mx = -INFINITY, sm = 0.f;
    const float* kbase = kpack + ((size_t)b * NN) * 8;
    int m0 = sp * 512;
#pragma unroll 2
    for (int m = m0; m < m0 + 512; ++m) {
        const float* kr = kbase + (size_t)m * 8;
        float d = 0.f;
#pragma unroll
        for (int o = 0; o < C8; ++o) d = fmaf(q[o], kr[o], d);
        float nm = fmaxf(mx, d);
        sm = sm * __expf(mx - nm) + __expf(d - nm);
        mx = nm;
    }
    pmax[((size_t)(b * 8 + sp)) * NN + n] = mx;
    psum[((size_t)(b * 8 + sp)) * NN + n] = sm;
}

// ---------------------------------------------------------------------------
// K2b: merge the 8 partials; write rowmax into qrec slot 8; scale vpack row
// by 1/rowsum (folds softmax denominator into V's columns).
// ---------------------------------------------------------------------------
__global__ void merge_scale(const float* __restrict__ pmax,
                            const float* __restrict__ psum,
                            float* __restrict__ qrec, float* __restrict__ vpack) {
    int gid = blockIdx.x * 256 + threadIdx.x;   // b*4096+n
    int b = gid >> 12;
    int n = gid & 4095;
    float pm[8];
    float gm = -INFINITY;
#pragma unroll
    for (int s = 0; s < 8; ++s) {
        pm[s] = pmax[((size_t)(b * 8 + s)) * NN + n];
        gm = fmaxf(gm, pm[s]);
    }
    float gs = 0.f;
#pragma unroll
    for (int s = 0; s < 8; ++s)
        gs += psum[((size_t)(b * 8 + s)) * NN + n] * __expf(pm[s] - gm);

    qrec[((size_t)gid) * 16 + 8] = gm;
    float inv = 1.0f / gs;
    float* vp = vpack + ((size_t)gid) * CC;
#pragma unroll
    for (int i = 0; i < 16; ++i) {
        float4 v = *(float4*)(vp + i * 4);
        v.x *= inv; v.y *= inv; v.z *= inv; v.w *= inv;
        *(float4*)(vp + i * 4) = v;
    }
}

// ---------------------------------------------------------------------------
// K3: out[b][c][m] = x + sum_n vscaled[c][n] * exp(dot(q[:,n],k[:,m]) - max[n])
// block: 64 m-lanes x 4 c-groups.  Per n: all shared operands wave-uniform
// (s_load), k per-lane in VGPRs, 16 accumulators per thread.
// ---------------------------------------------------------------------------
__global__ void attn_pv(const float* __restrict__ qrec,
                        const float* __restrict__ kpack,
                        const float* __restrict__ vpack,
                        const float* __restrict__ x, float* __restrict__ out) {
    int b = blockIdx.x >> 6;
    int mtile = blockIdx.x & 63;
    int ml = threadIdx.x & 63;
    int cgu = __builtin_amdgcn_readfirstlane((int)(threadIdx.x >> 6));
    int m = mtile * 64 + ml;

    const float* krp = kpack + ((size_t)(b * NN + m)) * 8;
    float k[C8];
#pragma unroll
    for (int o = 0; o < C8; ++o) k[o] = krp[o];

    float acc[16];
#pragma unroll
    for (int i = 0; i < 16; ++i) acc[i] = 0.f;

    const float* qb = qrec + ((size_t)b * NN) * 16;
    const float* vb = vpack + ((size_t)b * NN) * CC + cgu * 16;

#pragma unroll 2
    for (int nn = 0; nn < NN; ++nn) {
        const float* qr = qb + (size_t)nn * 16;
        float d = 0.f;
#pragma unroll
        for (int o = 0; o < C8; ++o) d = fmaf(qr[o], k[o], d);
        float p = __expf(d - qr[8]);
        const float* vr = vb + (size_t)nn * CC;
#pragma unroll
        for (int i = 0; i < 16; ++i) acc[i] = fmaf(vr[i], p, acc[i]);
    }

    size_t obase = ((size_t)(b * CC + cgu * 16)) * NN + m;
#pragma unroll
    for (int i = 0; i < 16; ++i)
        out[obase + (size_t)i * NN] = acc[i] + x[obase + (size_t)i * NN];
}

// ---------------------------------------------------------------------------
extern "C" void kernel_launch(void* const* d_in, const int* in_sizes, int n_in,
                              void* d_out, int out_size, void* d_ws, size_t ws_size,
                              hipStream_t stream) {
    const float* x  = (const float*)d_in[0];
    const float* wq = (const float*)d_in[1];
    const float* bq = (const float*)d_in[2];
    const float* wk = (const float*)d_in[3];
    const float* bk = (const float*)d_in[4];
    const float* wv = (const float*)d_in[5];
    const float* bv = (const float*)d_in[6];
    float* out = (float*)d_out;

    char* ws = (char*)d_ws;
    float* qrec  = (float*)ws;                                   // 4*4096*16*4 = 1 MB
    float* kpack = (float*)(ws + (1u << 20));                    // 512 KB
    float* vpack = (float*)(ws + (1u << 20) + (512u << 10));     // 4 MB
    float* pmax  = (float*)(ws + (1u << 20) + (512u << 10) + (4u << 20));  // 512 KB
    float* psum  = pmax + (size_t)NB * 8 * NN;                   // 512 KB

    proj_qk   <<<64,  256, 0, stream>>>(x, wq, bq, wk, bk, qrec, kpack);
    proj_v    <<<256, 256, 0, stream>>>(x, wv, bv, vpack);
    row_stats <<<512, 256, 0, stream>>>(qrec, kpack, pmax, psum);
    merge_scale<<<64, 256, 0, stream>>>(pmax, psum, qrec, vpack);
    attn_pv   <<<256, 256, 0, stream>>>(qrec, kpack, vpack, x, out);
}

// Round 2
// 100.065 us; speedup vs baseline: 11.6399x; 11.6399x over previous
//
#include <hip/hip_runtime.h>
#include <hip/hip_bf16.h>
#include <math.h>

#define NN 4096
#define CC 64
#define NB 4

typedef float f32x16 __attribute__((ext_vector_type(16)));
typedef short bf16x8 __attribute__((ext_vector_type(8)));
typedef short s16x4  __attribute__((ext_vector_type(4)));

static __device__ __forceinline__ short f2bf(float f) {
    __hip_bfloat16 h = __float2bfloat16(f);
    short s;
    __builtin_memcpy(&s, &h, 2);
    return s;
}

static __device__ __forceinline__ f32x16 fzero16() {
    f32x16 z;
#pragma unroll
    for (int i = 0; i < 16; ++i) z[i] = 0.f;
    return z;
}

static __device__ __forceinline__ bf16x8 bzero8() {
    bf16x8 z;
#pragma unroll
    for (int i = 0; i < 8; ++i) z[i] = 0;
    return z;
}

// ---------------------------------------------------------------------------
// K1: q,k projections -> bf16 fragment records qb[b][n][8], kb[b][m][8]
// ---------------------------------------------------------------------------
__global__ __launch_bounds__(64) void proj_qk(
        const float* __restrict__ x,
        const float* __restrict__ wq, const float* __restrict__ bq,
        const float* __restrict__ wk, const float* __restrict__ bk,
        short* __restrict__ qb, short* __restrict__ kb) {
    int gid = blockIdx.x * 64 + threadIdx.x;   // b*4096+n
    int b = gid >> 12;
    int n = gid & 4095;
    const float* xp = x + ((size_t)b * CC) * NN + n;
    float xr[CC];
#pragma unroll
    for (int c = 0; c < CC; ++c) xr[c] = xp[(size_t)c * NN];

    bf16x8 qv, kv;
#pragma unroll
    for (int o = 0; o < 8; ++o) {
        float sq = 0.f, sk = 0.f;
#pragma unroll
        for (int c = 0; c < CC; ++c) {
            sq = fmaf(wq[o * CC + c], xr[c], sq);
            sk = fmaf(wk[o * CC + c], xr[c], sk);
        }
        qv[o] = f2bf(sq + bq[o]);
        kv[o] = f2bf(sk + bk[o]);
    }
    *(bf16x8*)(qb + (size_t)gid * 8) = qv;
    *(bf16x8*)(kb + (size_t)gid * 8) = kv;
}

// ---------------------------------------------------------------------------
// K2: rinv[b][n] = 1 / sum_m exp(s[n][m]) via MFMA S-tiles.
// Block: (b, ntile64), 4 waves = wr(2 n-halves) x ws(2 m-splits).
// ---------------------------------------------------------------------------
__global__ __launch_bounds__(256) void stats_mfma(
        const short* __restrict__ qb, const short* __restrict__ kb,
        float* __restrict__ rinv) {
    int b = blockIdx.x >> 6;
    int nbase = (blockIdx.x & 63) << 6;
    int t = threadIdx.x;
    int w = __builtin_amdgcn_readfirstlane(t >> 6);
    int ml = t & 31;
    int hi = (t >> 5) & 1;
    int wr = w & 1;
    int ws = w >> 1;

    bf16x8 qf = bzero8();
    if (hi == 0)
        qf = *(const bf16x8*)(qb + ((size_t)(b * NN + nbase + 32 * wr + ml)) * 8);

    float acc[16];
#pragma unroll
    for (int r = 0; r < 16; ++r) acc[r] = 0.f;

    const short* kbb = kb + ((size_t)b * NN) * 8;
    bf16x8 kf = bzero8();
    if (hi == 0) kf = *(const bf16x8*)(kbb + ((size_t)(ws * 32 + ml)) * 8);

    for (int mch = ws; mch < 128; mch += 2) {
        f32x16 s = __builtin_amdgcn_mfma_f32_32x32x16_bf16(qf, kf, fzero16(), 0, 0, 0);
        if (mch + 2 < 128 && hi == 0)
            kf = *(const bf16x8*)(kbb + ((size_t)((mch + 2) * 32 + ml)) * 8);
#pragma unroll
        for (int r = 0; r < 16; ++r) acc[r] += __expf(s[r]);
    }

#pragma unroll
    for (int r = 0; r < 16; ++r) {
#pragma unroll
        for (int mask = 1; mask <= 16; mask <<= 1)
            acc[r] += __shfl_xor(acc[r], mask);
    }

    __shared__ float rs[64];
    if (t < 64) rs[t] = 0.f;
    __syncthreads();
    if (ml == 0) {
#pragma unroll
        for (int r = 0; r < 16; ++r) {
            int rowr = (r & 3) + 8 * (r >> 2) + 4 * hi;
            atomicAdd(&rs[32 * wr + rowr], acc[r]);
        }
    }
    __syncthreads();
    if (t < 64) rinv[(size_t)b * NN + nbase + t] = 1.0f / rs[t];
}

// ---------------------------------------------------------------------------
// K3: v projection, scaled by rinv[n] -> vsT[b][c][n] bf16
// ---------------------------------------------------------------------------
__global__ __launch_bounds__(64) void proj_v(
        const float* __restrict__ x,
        const float* __restrict__ wv, const float* __restrict__ bv,
        const float* __restrict__ rinv, short* __restrict__ vsT) {
    int gid = blockIdx.x * 64 + threadIdx.x;   // 32768 threads
    int b = gid >> 13;
    int ch = (gid >> 12) & 1;
    int n = gid & 4095;
    const float* xp = x + ((size_t)b * CC) * NN + n;
    float xr[CC];
#pragma unroll
    for (int c = 0; c < CC; ++c) xr[c] = xp[(size_t)c * NN];

    float inv = rinv[(size_t)b * NN + n];
    int c0 = 32 * ch;
#pragma unroll
    for (int i = 0; i < 32; ++i) {
        int c = c0 + i;
        float s = 0.f;
#pragma unroll
        for (int cc = 0; cc < CC; ++cc) s = fmaf(wv[c * CC + cc], xr[cc], s);
        vsT[((size_t)(b * CC + c)) * NN + n] = f2bf((s + bv[c]) * inv);
    }
}

// ---------------------------------------------------------------------------
// K4: out[b][c][m] = x + sum_n Vs[c][n] * exp(s[n][m])
// Block: (b, mtile64), 8 waves = ws(2 n-splits) x wr(2 c-halves) x wc(2 m-halves)
// Per 64-n chunk: S MFMA -> exp -> P_T to LDS (dbuf) -> 4 PV MFMAs.
// P_T row stride 136 B: bank stride 2 -> 2-way conflicts (free).
// ---------------------------------------------------------------------------
#define PT_ROW 136
#define PT_BUF 4352          // 32 * 136
#define PT_HALF 17408        // 4 bufs

__global__ __launch_bounds__(512) void attn_pv(
        const short* __restrict__ qb, const short* __restrict__ kb,
        const short* __restrict__ vsT,
        const float* __restrict__ x, float* __restrict__ out) {
    __shared__ char lds[2 * PT_HALF];

    int b = blockIdx.x >> 6;
    int mbase = (blockIdx.x & 63) << 6;
    int t = threadIdx.x;
    int w = __builtin_amdgcn_readfirstlane(t >> 6);
    int ml = t & 31;
    int hi = (t >> 5) & 1;
    int ws = w >> 2;
    int wr = (w >> 1) & 1;
    int wc = w & 1;

    // hoisted k fragment (S B-operand): m = mbase + 32*wc + ml, ch 0..7 in lo lanes
    bf16x8 kf = bzero8();
    if (hi == 0)
        kf = *(const bf16x8*)(kb + ((size_t)(b * NN + mbase + 32 * wc + ml)) * 8);

    f32x16 acc = fzero16();

    const short* qbb = qb + ((size_t)b * NN) * 8;
    const short* vrow = vsT + ((size_t)(b * CC + 32 * wr + ml)) * NN;

    bf16x8 qf = bzero8();
    if (hi == 0) qf = *(const bf16x8*)(qbb + ((size_t)(ws * 64 + 32 * wr + ml)) * 8);

    int parity = 0;
    int lds_off = (ws * 2 + wc) * PT_BUF + ml * PT_ROW;

    for (int nb = ws; nb < 64; nb += 2) {
        f32x16 s = __builtin_amdgcn_mfma_f32_32x32x16_bf16(qf, kf, fzero16(), 0, 0, 0);

        // prefetch next q fragment
        if (nb + 2 < 64 && hi == 0)
            qf = *(const bf16x8*)(qbb + ((size_t)((nb + 2) * 64 + 32 * wr + ml)) * 8);

        // prefetch Vs A-fragments for this chunk (independent of LDS)
        bf16x8 af[4];
#pragma unroll
        for (int tt = 0; tt < 4; ++tt)
            af[tt] = *(const bf16x8*)(vrow + nb * 64 + 16 * tt + 8 * hi);

        // exp + pack + write P_T
        float pe[16];
#pragma unroll
        for (int r = 0; r < 16; ++r) pe[r] = __expf(s[r]);

        char* wbase = lds + parity * PT_HALF + lds_off + (64 * wr + 8 * hi);
#pragma unroll
        for (int g = 0; g < 4; ++g) {
            s16x4 pk;
            pk[0] = f2bf(pe[4 * g + 0]);
            pk[1] = f2bf(pe[4 * g + 1]);
            pk[2] = f2bf(pe[4 * g + 2]);
            pk[3] = f2bf(pe[4 * g + 3]);
            *(s16x4*)(wbase + g * 16) = pk;
        }

        __syncthreads();

        // PV: 4 MFMAs, B-frags from LDS P_T, A-frags = af[]
        char* rbase = lds + parity * PT_HALF + lds_off + 16 * hi;
#pragma unroll
        for (int tt = 0; tt < 4; ++tt) {
            s16x4 b0 = *(s16x4*)(rbase + tt * 32);
            s16x4 b1 = *(s16x4*)(rbase + tt * 32 + 8);
            bf16x8 bf;
#pragma unroll
            for (int j = 0; j < 4; ++j) { bf[j] = b0[j]; bf[4 + j] = b1[j]; }
            acc = __builtin_amdgcn_mfma_f32_32x32x16_bf16(af[tt], bf, acc, 0, 0, 0);
        }
        parity ^= 1;
    }

    // reduce ws partials via LDS, add residual, store
    __syncthreads();
    float* red = (float*)lds;
    if (ws == 1) {
#pragma unroll
        for (int r = 0; r < 16; ++r) {
            int rowr = (r & 3) + 8 * (r >> 2) + 4 * hi;
            red[(32 * wr + rowr) * 64 + 32 * wc + ml] = acc[r];
        }
    }
    __syncthreads();
    if (ws == 0) {
#pragma unroll
        for (int r = 0; r < 16; ++r) {
            int rowr = (r & 3) + 8 * (r >> 2) + 4 * hi;
            int c = 32 * wr + rowr;
            int m = mbase + 32 * wc + ml;
            size_t idx = ((size_t)(b * CC + c)) * NN + m;
            out[idx] = acc[r] + red[(32 * wr + rowr) * 64 + 32 * wc + ml] + x[idx];
        }
    }
}

// ---------------------------------------------------------------------------
extern "C" void kernel_launch(void* const* d_in, const int* in_sizes, int n_in,
                              void* d_out, int out_size, void* d_ws, size_t ws_size,
                              hipStream_t stream) {
    const float* x  = (const float*)d_in[0];
    const float* wq = (const float*)d_in[1];
    const float* bq = (const float*)d_in[2];
    const float* wk = (const float*)d_in[3];
    const float* bk = (const float*)d_in[4];
    const float* wv = (const float*)d_in[5];
    const float* bv = (const float*)d_in[6];
    float* out = (float*)d_out;

    char* ws = (char*)d_ws;
    short* qb16 = (short*)(ws);                 // 256 KB
    short* kb16 = (short*)(ws + (256u << 10));  // 256 KB
    short* vsT  = (short*)(ws + (512u << 10));  // 2 MB
    float* rinv = (float*)(ws + (512u << 10) + (2u << 20));  // 64 KB

    proj_qk   <<<256, 64,  0, stream>>>(x, wq, bq, wk, bk, qb16, kb16);
    stats_mfma<<<256, 256, 0, stream>>>(qb16, kb16, rinv);
    proj_v    <<<512, 64,  0, stream>>>(x, wv, bv, rinv, vsT);
    attn_pv   <<<256, 512, 0, stream>>>(qb16, kb16, vsT, x, out);
}

// Round 3
// 71.468 us; speedup vs baseline: 16.2975x; 1.4001x over previous
//
#include <hip/hip_runtime.h>
#include <hip/hip_bf16.h>
#include <math.h>

#define NN 4096
#define CC 64

typedef float  f32x16 __attribute__((ext_vector_type(16)));
typedef short  bf16x8 __attribute__((ext_vector_type(8)));
typedef short  s16x4  __attribute__((ext_vector_type(4)));
typedef unsigned int u32x4 __attribute__((ext_vector_type(4)));

static __device__ __forceinline__ unsigned short f2bfu(float f) {
    __hip_bfloat16 h = __float2bfloat16(f);
    unsigned short s;
    __builtin_memcpy(&s, &h, 2);
    return s;
}
static __device__ __forceinline__ unsigned packbf(float lo, float hi) {
    return (unsigned)f2bfu(lo) | ((unsigned)f2bfu(hi) << 16);
}
static __device__ __forceinline__ f32x16 fzero16() {
    f32x16 z;
#pragma unroll
    for (int i = 0; i < 16; ++i) z[i] = 0.f;
    return z;
}
static __device__ __forceinline__ bf16x8 bzero8() {
    bf16x8 z;
#pragma unroll
    for (int i = 0; i < 8; ++i) z[i] = 0;
    return z;
}

// ---------------------------------------------------------------------------
// K0: pack W[96][64] bf16 (rows 0-7 q, 8-15 k, 16-79 v, 80-95 zero) + bias[96]
// ---------------------------------------------------------------------------
__global__ __launch_bounds__(256) void w_pack(
        const float* __restrict__ wq, const float* __restrict__ bq,
        const float* __restrict__ wk, const float* __restrict__ bk,
        const float* __restrict__ wv, const float* __restrict__ bv,
        short* __restrict__ Wp, float* __restrict__ biasp) {
    int t = threadIdx.x;
    for (int idx = t; idx < 96 * 64; idx += 256) {
        int row = idx >> 6, c = idx & 63;
        float v = 0.f;
        if (row < 8)       v = wq[row * 64 + c];
        else if (row < 16) v = wk[(row - 8) * 64 + c];
        else if (row < 80) v = wv[(row - 16) * 64 + c];
        Wp[idx] = (short)f2bfu(v);
    }
    if (t < 96) {
        float v = 0.f;
        if (t < 8)       v = bq[t];
        else if (t < 16) v = bk[t - 8];
        else if (t < 80) v = bv[t - 16];
        biasp[t] = v;
    }
}

// ---------------------------------------------------------------------------
// K1: MFMA projection. One wave per 32-n tile; 3 m-tiles (96 rows) x 4 k-steps.
// Writes qb[n][8] bf16, kb[n][8] bf16, vT[b][c][n] fp32 (unscaled).
// ---------------------------------------------------------------------------
__global__ __launch_bounds__(256) void proj_mfma(
        const float* __restrict__ x,
        const short* __restrict__ Wp, const float* __restrict__ biasp,
        short* __restrict__ qb, short* __restrict__ kb, float* __restrict__ vT) {
    int t = threadIdx.x;
    int w = __builtin_amdgcn_readfirstlane(t >> 6);
    int ml = t & 31, hi = (t >> 5) & 1;
    int nt = blockIdx.x * 4 + w;
    int ng = nt * 32 + ml;            // global col index (b*4096+n)
    int b = ng >> 12;
    int nb_ = ng & 4095;
    const float* xc = x + ((size_t)b * CC) * NN + nb_;

    f32x16 acc0 = fzero16(), acc1 = fzero16(), acc2 = fzero16();

#pragma unroll
    for (int s = 0; s < 4; ++s) {
        int c0 = 16 * s + 8 * hi;
        float xv[8];
#pragma unroll
        for (int j = 0; j < 8; ++j) xv[j] = xc[(size_t)(c0 + j) * NN];
        u32x4 xg;
#pragma unroll
        for (int j = 0; j < 4; ++j) xg[j] = packbf(xv[2 * j], xv[2 * j + 1]);
        bf16x8 xf = __builtin_bit_cast(bf16x8, xg);

        bf16x8 a0 = *(const bf16x8*)(Wp + (size_t)(0 * 32 + ml) * 64 + c0);
        bf16x8 a1 = *(const bf16x8*)(Wp + (size_t)(1 * 32 + ml) * 64 + c0);
        bf16x8 a2 = *(const bf16x8*)(Wp + (size_t)(2 * 32 + ml) * 64 + c0);
        acc0 = __builtin_amdgcn_mfma_f32_32x32x16_bf16(a0, xf, acc0, 0, 0, 0);
        acc1 = __builtin_amdgcn_mfma_f32_32x32x16_bf16(a1, xf, acc1, 0, 0, 0);
        acc2 = __builtin_amdgcn_mfma_f32_32x32x16_bf16(a2, xf, acc2, 0, 0, 0);
    }

    // epilogue: D row = (r&3)+8*(r>>2)+4*hi (+32*mt), col = ml
    // q rows 0-7 / k rows 8-15: this lane holds exactly half of each record
    s16x4 qv, kv;
#pragma unroll
    for (int r = 0; r < 4; ++r) {
        qv[r] = (short)f2bfu(acc0[r] + biasp[r + 4 * hi]);
        kv[r] = (short)f2bfu(acc0[r + 4] + biasp[8 + r + 4 * hi]);
    }
    *(s16x4*)(qb + (size_t)ng * 8 + 4 * hi) = qv;
    *(s16x4*)(kb + (size_t)ng * 8 + 4 * hi) = kv;

    float* vbase = vT + ((size_t)b * CC) * NN + nb_;
#pragma unroll
    for (int r = 8; r < 16; ++r) {          // mt0 rows 16-31 -> v c 0-15
        int rowr = (r & 3) + 8 * (r >> 2) + 4 * hi;
        vbase[(size_t)(rowr - 16) * NN] = acc0[r] + biasp[rowr];
    }
#pragma unroll
    for (int r = 0; r < 16; ++r) {          // mt1 rows 32-63 -> v c 16-47
        int rowr = (r & 3) + 8 * (r >> 2) + 4 * hi;
        vbase[(size_t)(rowr + 16) * NN] = acc1[r] + biasp[32 + rowr];
    }
#pragma unroll
    for (int r = 0; r < 8; ++r) {           // mt2 rows 64-79 -> v c 48-63
        int rowr = (r & 3) + 8 * (r >> 2) + 4 * hi;
        vbase[(size_t)(rowr + 48) * NN] = acc2[r] + biasp[64 + rowr];
    }
}

// ---------------------------------------------------------------------------
// K2: rinv[b][n] = 1/sum_m exp(s[n][m]).  512 blocks x 4 waves (m-split 4).
// ---------------------------------------------------------------------------
__global__ __launch_bounds__(256) void stats_mfma(
        const short* __restrict__ qb, const short* __restrict__ kb,
        float* __restrict__ rinv) {
    int b = blockIdx.x >> 7;
    int n0g = (blockIdx.x & 127) * 32;
    int t = threadIdx.x;
    int w = __builtin_amdgcn_readfirstlane(t >> 6);
    int ml = t & 31, hi = (t >> 5) & 1;

    bf16x8 qf = bzero8();
    if (!hi) qf = *(const bf16x8*)(qb + ((size_t)(b * NN + n0g + ml)) * 8);

    const short* kbb = kb + ((size_t)b * NN) * 8;
    bf16x8 kf = bzero8();
    if (!hi) kf = *(const bf16x8*)(kbb + (size_t)(w * 32 + ml) * 8);

    float accl[16];
#pragma unroll
    for (int r = 0; r < 16; ++r) accl[r] = 0.f;

    for (int i = 0; i < 32; ++i) {
        f32x16 s = __builtin_amdgcn_mfma_f32_32x32x16_bf16(qf, kf, fzero16(), 0, 0, 0);
        if (!hi && i + 1 < 32)
            kf = *(const bf16x8*)(kbb + (size_t)((w + 4 * (i + 1)) * 32 + ml) * 8);
#pragma unroll
        for (int r = 0; r < 16; ++r) accl[r] += __expf(s[r]);
    }

#pragma unroll
    for (int r = 0; r < 16; ++r) {
#pragma unroll
        for (int mask = 1; mask <= 16; mask <<= 1)
            accl[r] += __shfl_xor(accl[r], mask);
    }

    __shared__ float rs[32];
    if (t < 32) rs[t] = 0.f;
    __syncthreads();
    if (ml == 0) {
#pragma unroll
        for (int r = 0; r < 16; ++r) {
            int rowr = (r & 3) + 8 * (r >> 2) + 4 * hi;
            atomicAdd(&rs[rowr], accl[r]);
        }
    }
    __syncthreads();
    if (t < 32) rinv[(size_t)b * NN + n0g + t] = 1.0f / rs[t];
}

// ---------------------------------------------------------------------------
// K3: vsT[c][n] = bf16(vT[c][n] * rinv[n])
// ---------------------------------------------------------------------------
__global__ __launch_bounds__(256) void v_scale(
        const float* __restrict__ vT, const float* __restrict__ rinv,
        short* __restrict__ vsT) {
    int gid = blockIdx.x * 256 + threadIdx.x;   // 131072 threads, 8 elems each
    int row = gid >> 9;                         // b*64+c
    int noff = (gid & 511) << 3;
    int b = row >> 6;
    const float* vp = vT + (size_t)row * NN + noff;
    const float* rp = rinv + (size_t)b * NN + noff;
    float4 v0 = *(const float4*)vp, v1 = *(const float4*)(vp + 4);
    float4 r0 = *(const float4*)rp, r1 = *(const float4*)(rp + 4);
    u32x4 o;
    o[0] = packbf(v0.x * r0.x, v0.y * r0.y);
    o[1] = packbf(v0.z * r0.z, v0.w * r0.w);
    o[2] = packbf(v1.x * r1.x, v1.y * r1.y);
    o[3] = packbf(v1.z * r1.z, v1.w * r1.w);
    *(u32x4*)(vsT + (size_t)row * NN + noff) = o;
}

// ---------------------------------------------------------------------------
// K4: out[b][c][m] = x + sum_n Vs[c][n] * exp(s[n][m]).
// 8 waves = ws(chunk parity) x sr(row half) x wc(m half).  No loop barriers:
// P stays in registers; PV B-frag built via 4 shfl_xor(32) partner exchanges.
// ---------------------------------------------------------------------------
__global__ __launch_bounds__(512) void attn_pv(
        const short* __restrict__ qb, const short* __restrict__ kb,
        const short* __restrict__ vsT,
        const float* __restrict__ x, float* __restrict__ out) {
    __shared__ float red[4][64][68];

    int b = blockIdx.x >> 6;
    int mbase = (blockIdx.x & 63) << 6;
    int t = threadIdx.x;
    int w = __builtin_amdgcn_readfirstlane(t >> 6);
    int ml = t & 31, hi = (t >> 5) & 1;
    int ws = w >> 2, sr = (w >> 1) & 1, wc = w & 1;

    bf16x8 kf = bzero8();
    if (!hi) kf = *(const bf16x8*)(kb + ((size_t)(b * NN + mbase + 32 * wc + ml)) * 8);

    f32x16 acc0 = fzero16(), acc1 = fzero16();
    const short* qbb = qb + ((size_t)b * NN) * 8;
    const short* v0p = vsT + ((size_t)(b * CC) + ml) * NN;
    const short* v1p = vsT + ((size_t)(b * CC) + 32 + ml) * NN;

    for (int nb2 = ws; nb2 < 64; nb2 += 2) {
        int n0 = nb2 * 64 + 32 * sr;

        bf16x8 qf = bzero8();
        if (!hi) qf = *(const bf16x8*)(qbb + (size_t)(n0 + ml) * 8);

        bf16x8 a00 = *(const bf16x8*)(v0p + n0 + 8 * hi);
        bf16x8 a01 = *(const bf16x8*)(v0p + n0 + 16 + 8 * hi);
        bf16x8 a10 = *(const bf16x8*)(v1p + n0 + 8 * hi);
        bf16x8 a11 = *(const bf16x8*)(v1p + n0 + 16 + 8 * hi);

        f32x16 s = __builtin_amdgcn_mfma_f32_32x32x16_bf16(qf, kf, fzero16(), 0, 0, 0);

        // pack exp(P) to bf16 pairs: g[j] <-> rows {2j,2j+1} of my row set
        unsigned g0 = packbf(__expf(s[0]),  __expf(s[1]));
        unsigned g1 = packbf(__expf(s[2]),  __expf(s[3]));
        unsigned g2 = packbf(__expf(s[4]),  __expf(s[5]));
        unsigned g3 = packbf(__expf(s[6]),  __expf(s[7]));
        unsigned g4 = packbf(__expf(s[8]),  __expf(s[9]));
        unsigned g5 = packbf(__expf(s[10]), __expf(s[11]));
        unsigned g6 = packbf(__expf(s[12]), __expf(s[13]));
        unsigned g7 = packbf(__expf(s[14]), __expf(s[15]));

        // partner exchange (lane <-> lane^32): I need partner's {g0,g1,g4,g5}
        // if hi==0, partner's {g2,g3,g6,g7} if hi==1
        unsigned r0 = (unsigned)__shfl_xor((int)(hi ? g0 : g2), 32);
        unsigned r1 = (unsigned)__shfl_xor((int)(hi ? g1 : g3), 32);
        unsigned r2 = (unsigned)__shfl_xor((int)(hi ? g4 : g6), 32);
        unsigned r3 = (unsigned)__shfl_xor((int)(hi ? g5 : g7), 32);

        u32x4 b0u, b1u;
        b0u[0] = hi ? r0 : g0;  b0u[1] = hi ? r1 : g1;
        b0u[2] = hi ? g2 : r0;  b0u[3] = hi ? g3 : r1;
        b1u[0] = hi ? r2 : g4;  b1u[1] = hi ? r3 : g5;
        b1u[2] = hi ? g6 : r2;  b1u[3] = hi ? g7 : r3;
        bf16x8 bf0 = __builtin_bit_cast(bf16x8, b0u);
        bf16x8 bf1 = __builtin_bit_cast(bf16x8, b1u);

        acc0 = __builtin_amdgcn_mfma_f32_32x32x16_bf16(a00, bf0, acc0, 0, 0, 0);
        acc0 = __builtin_amdgcn_mfma_f32_32x32x16_bf16(a01, bf1, acc0, 0, 0, 0);
        acc1 = __builtin_amdgcn_mfma_f32_32x32x16_bf16(a10, bf0, acc1, 0, 0, 0);
        acc1 = __builtin_amdgcn_mfma_f32_32x32x16_bf16(a11, bf1, acc1, 0, 0, 0);
    }

    int quad = ws * 2 + sr;
#pragma unroll
    for (int r = 0; r < 16; ++r) {
        int rowr = (r & 3) + 8 * (r >> 2) + 4 * hi;
        red[quad][rowr][32 * wc + ml] = acc0[r];
        red[quad][rowr + 32][32 * wc + ml] = acc1[r];
    }
    __syncthreads();

    int c = t >> 3;
    int m0 = (t & 7) << 3;
    float4 s0 = *(float4*)&red[0][c][m0];
    float4 s1 = *(float4*)&red[0][c][m0 + 4];
#pragma unroll
    for (int q = 1; q < 4; ++q) {
        float4 a = *(float4*)&red[q][c][m0];
        float4 bq4 = *(float4*)&red[q][c][m0 + 4];
        s0.x += a.x; s0.y += a.y; s0.z += a.z; s0.w += a.w;
        s1.x += bq4.x; s1.y += bq4.y; s1.z += bq4.z; s1.w += bq4.w;
    }
    size_t idx = ((size_t)(b * CC + c)) * NN + mbase + m0;
    float4 xa = *(const float4*)(x + idx);
    float4 xb2 = *(const float4*)(x + idx + 4);
    s0.x += xa.x; s0.y += xa.y; s0.z += xa.z; s0.w += xa.w;
    s1.x += xb2.x; s1.y += xb2.y; s1.z += xb2.z; s1.w += xb2.w;
    *(float4*)(out + idx) = s0;
    *(float4*)(out + idx + 4) = s1;
}

// ---------------------------------------------------------------------------
extern "C" void kernel_launch(void* const* d_in, const int* in_sizes, int n_in,
                              void* d_out, int out_size, void* d_ws, size_t ws_size,
                              hipStream_t stream) {
    const float* x  = (const float*)d_in[0];
    const float* wq = (const float*)d_in[1];
    const float* bq = (const float*)d_in[2];
    const float* wk = (const float*)d_in[3];
    const float* bk = (const float*)d_in[4];
    const float* wv = (const float*)d_in[5];
    const float* bv = (const float*)d_in[6];
    float* out = (float*)d_out;

    char* ws = (char*)d_ws;
    short* qb   = (short*)(ws);                              // 256 KB
    short* kb   = (short*)(ws + (256u << 10));               // 256 KB
    float* vT   = (float*)(ws + (512u << 10));               // 4 MB
    short* vsT  = (short*)(ws + (512u << 10) + (4u << 20));  // 2 MB
    float* rinv = (float*)(ws + (512u << 10) + (6u << 20));  // 64 KB
    short* Wp   = (short*)(ws + (640u << 10) + (6u << 20));  // 12 KB
    float* biasp= (float*)(ws + (672u << 10) + (6u << 20));  // 384 B

    w_pack    <<<1,   256, 0, stream>>>(wq, bq, wk, bk, wv, bv, Wp, biasp);
    proj_mfma <<<128, 256, 0, stream>>>(x, Wp, biasp, qb, kb, vT);
    stats_mfma<<<512, 256, 0, stream>>>(qb, kb, rinv);
    v_scale   <<<512, 256, 0, stream>>>(vT, rinv, vsT);
    attn_pv   <<<256, 512, 0, stream>>>(qb, kb, vsT, x, out);
}

// Round 5
// 63.163 us; speedup vs baseline: 18.4405x; 1.1315x over previous
//
#include <hip/hip_runtime.h>
#include <hip/hip_bf16.h>
#include <math.h>

#define NN 4096
#define CC 64

typedef float  f32x16 __attribute__((ext_vector_type(16)));
typedef short  bf16x8 __attribute__((ext_vector_type(8)));
typedef short  s16x4  __attribute__((ext_vector_type(4)));
typedef unsigned int u32x4 __attribute__((ext_vector_type(4)));

static __device__ __forceinline__ unsigned short f2bfu(float f) {
    __hip_bfloat16 h = __float2bfloat16(f);
    unsigned short s;
    __builtin_memcpy(&s, &h, 2);
    return s;
}
static __device__ __forceinline__ unsigned packbf(float lo, float hi) {
    return (unsigned)f2bfu(lo) | ((unsigned)f2bfu(hi) << 16);
}
static __device__ __forceinline__ f32x16 fzero16() {
    f32x16 z;
#pragma unroll
    for (int i = 0; i < 16; ++i) z[i] = 0.f;
    return z;
}
static __device__ __forceinline__ bf16x8 bzero8() {
    bf16x8 z;
#pragma unroll
    for (int i = 0; i < 8; ++i) z[i] = 0;
    return z;
}

// ---------------------------------------------------------------------------
// K0: pack W[96][64] bf16 (rows 0-7 q, 8-15 k, 16-79 v, 80-95 zero) + bias[96]
// ---------------------------------------------------------------------------
__global__ __launch_bounds__(256) void w_pack(
        const float* __restrict__ wq, const float* __restrict__ bq,
        const float* __restrict__ wk, const float* __restrict__ bk,
        const float* __restrict__ wv, const float* __restrict__ bv,
        short* __restrict__ Wp, float* __restrict__ biasp) {
    int t = threadIdx.x;
    for (int idx = t; idx < 96 * 64; idx += 256) {
        int row = idx >> 6, c = idx & 63;
        float v = 0.f;
        if (row < 8)       v = wq[row * 64 + c];
        else if (row < 16) v = wk[(row - 8) * 64 + c];
        else if (row < 80) v = wv[(row - 16) * 64 + c];
        Wp[idx] = (short)f2bfu(v);
    }
    if (t < 96) {
        float v = 0.f;
        if (t < 8)       v = bq[t];
        else if (t < 16) v = bk[t - 8];
        else if (t < 80) v = bv[t - 16];
        biasp[t] = v;
    }
}

// ---------------------------------------------------------------------------
// K1: q,k projection via MFMA.  One wave per 32-n tile (grid 512).
// A = Wp rows 0-31 (q rows 0-7, k rows 8-15; rows 16-31 computed, discarded).
// Writes qb[n][8], kb[n][8] bf16 fragment records.
// ---------------------------------------------------------------------------
__global__ __launch_bounds__(64) void proj_qk(
        const float* __restrict__ x,
        const short* __restrict__ Wp, const float* __restrict__ biasp,
        short* __restrict__ qb, short* __restrict__ kb) {
    int t = threadIdx.x;
    int ml = t & 31, hi = t >> 5;
    int ng = blockIdx.x * 32 + ml;    // b*4096+n
    int b = ng >> 12;
    int nb_ = ng & 4095;
    const float* xc = x + ((size_t)b * CC) * NN + nb_;

    f32x16 acc = fzero16();
#pragma unroll
    for (int s = 0; s < 4; ++s) {
        int c0 = 16 * s + 8 * hi;
        float xv[8];
#pragma unroll
        for (int j = 0; j < 8; ++j) xv[j] = xc[(size_t)(c0 + j) * NN];
        u32x4 xg;
#pragma unroll
        for (int j = 0; j < 4; ++j) xg[j] = packbf(xv[2 * j], xv[2 * j + 1]);
        bf16x8 xf = __builtin_bit_cast(bf16x8, xg);
        bf16x8 af = *(const bf16x8*)(Wp + (size_t)ml * 64 + c0);
        acc = __builtin_amdgcn_mfma_f32_32x32x16_bf16(af, xf, acc, 0, 0, 0);
    }

    // D rows: lane holds rows (r&3)+8*(r>>2)+4*hi, col = ml.
    // q channels 0-7 <- acc[0..3] (rows 0-7), k channels <- acc[4..7] (rows 8-15)
    s16x4 qv, kv;
#pragma unroll
    for (int j = 0; j < 4; ++j) {
        qv[j] = (short)f2bfu(acc[j] + biasp[j + 4 * hi]);
        kv[j] = (short)f2bfu(acc[j + 4] + biasp[8 + j + 4 * hi]);
    }
    *(s16x4*)(qb + (size_t)ng * 8 + 4 * hi) = qv;
    *(s16x4*)(kb + (size_t)ng * 8 + 4 * hi) = kv;
}

// ---------------------------------------------------------------------------
// K2: rinv[b][n] = 1/sum_m exp(s[n][m]).  Grid 512 = b x 128 n-tiles(32);
// 8 waves m-split, 16 iters each, 1-deep k-fragment prefetch.
// ---------------------------------------------------------------------------
__global__ __launch_bounds__(512) void stats_mfma(
        const short* __restrict__ qb, const short* __restrict__ kb,
        float* __restrict__ rinv) {
    int b = blockIdx.x >> 7;
    int nbase = (blockIdx.x & 127) * 32;
    int t = threadIdx.x;
    int w = __builtin_amdgcn_readfirstlane(t >> 6);
    int ml = t & 31, hi = (t >> 5) & 1;

    bf16x8 qf = bzero8();
    if (!hi) qf = *(const bf16x8*)(qb + ((size_t)(b * NN + nbase + ml)) * 8);
    const short* kbb = kb + ((size_t)b * NN) * 8;

    float accl[16];
#pragma unroll
    for (int r = 0; r < 16; ++r) accl[r] = 0.f;

    bf16x8 kf0 = bzero8();
    if (!hi) kf0 = *(const bf16x8*)(kbb + (size_t)(w * 32 + ml) * 8);

    for (int i = 0; i < 16; ++i) {
        int mchn = (i < 15) ? (w + 8 * (i + 1)) : w;
        bf16x8 kf1 = bzero8();
        if (!hi) kf1 = *(const bf16x8*)(kbb + (size_t)(mchn * 32 + ml) * 8);
        f32x16 s = __builtin_amdgcn_mfma_f32_32x32x16_bf16(qf, kf0, fzero16(), 0, 0, 0);
#pragma unroll
        for (int r = 0; r < 16; ++r) accl[r] += __expf(s[r]);
        kf0 = kf1;
    }

#pragma unroll
    for (int r = 0; r < 16; ++r) {
#pragma unroll
        for (int mask = 1; mask <= 16; mask <<= 1)
            accl[r] += __shfl_xor(accl[r], mask);
    }

    __shared__ float rs[32];
    if (t < 32) rs[t] = 0.f;
    __syncthreads();
    if (ml == 0) {
#pragma unroll
        for (int r = 0; r < 16; ++r) {
            int rowr = (r & 3) + 8 * (r >> 2) + 4 * hi;
            atomicAdd(&rs[rowr], accl[r]);
        }
    }
    __syncthreads();
    if (t < 32) rinv[(size_t)b * NN + nbase + t] = 1.0f / rs[t];
}

// ---------------------------------------------------------------------------
// K3: v projection via MFMA, rinv folded in epilogue -> vsT[b*64+c][n] bf16.
// Grid 1024 waves = vt(2 row-tiles: Wp rows 16-47 / 48-79) x nt(512 n-tiles).
// ---------------------------------------------------------------------------
__global__ __launch_bounds__(64) void proj_v(
        const float* __restrict__ x,
        const short* __restrict__ Wp, const float* __restrict__ biasp,
        const float* __restrict__ rinv, short* __restrict__ vsT) {
    int t = threadIdx.x;
    int ml = t & 31, hi = t >> 5;
    int vt = blockIdx.x >> 9;         // 0..1
    int nt = blockIdx.x & 511;
    int ng = nt * 32 + ml;
    int b = ng >> 12;
    int nb_ = ng & 4095;
    const float* xc = x + ((size_t)b * CC) * NN + nb_;

    f32x16 acc = fzero16();
#pragma unroll
    for (int s = 0; s < 4; ++s) {
        int c0 = 16 * s + 8 * hi;
        float xv[8];
#pragma unroll
        for (int j = 0; j < 8; ++j) xv[j] = xc[(size_t)(c0 + j) * NN];
        u32x4 xg;
#pragma unroll
        for (int j = 0; j < 4; ++j) xg[j] = packbf(xv[2 * j], xv[2 * j + 1]);
        bf16x8 xf = __builtin_bit_cast(bf16x8, xg);
        bf16x8 af = *(const bf16x8*)(Wp + (size_t)(16 + 32 * vt + ml) * 64 + c0);
        acc = __builtin_amdgcn_mfma_f32_32x32x16_bf16(af, xf, acc, 0, 0, 0);
    }

    float inv = rinv[(size_t)b * NN + nb_];
#pragma unroll
    for (int r = 0; r < 16; ++r) {
        int rowr = (r & 3) + 8 * (r >> 2) + 4 * hi;
        int c = 32 * vt + rowr;
        vsT[((size_t)(b * CC + c)) * NN + nb_] =
            (short)f2bfu((acc[r] + biasp[16 + c]) * inv);
    }
}

// ---------------------------------------------------------------------------
// K4: out[b][c][m] = x + sum_n Vs[c][n] * exp(s[n][m]).
// Grid 512 = b x 128 m-tiles(32); 4 waves n-split, 32 iters, 1-deep prefetch.
// P in registers; PV B-frag via shfl_xor(32) partner exchange; no loop barriers.
// ---------------------------------------------------------------------------
__global__ __launch_bounds__(256) void attn_pv(
        const short* __restrict__ qb, const short* __restrict__ kb,
        const short* __restrict__ vsT,
        const float* __restrict__ x, float* __restrict__ out) {
    __shared__ float red[4][64][33];

    int b = blockIdx.x >> 7;
    int mbase = (blockIdx.x & 127) * 32;
    int t = threadIdx.x;
    int w = __builtin_amdgcn_readfirstlane(t >> 6);
    int ml = t & 31, hi = (t >> 5) & 1;

    bf16x8 kf = bzero8();
    if (!hi) kf = *(const bf16x8*)(kb + ((size_t)(b * NN + mbase + ml)) * 8);

    f32x16 acc0 = fzero16(), acc1 = fzero16();
    const short* qbb = qb + ((size_t)b * NN) * 8;
    const short* v0p = vsT + ((size_t)(b * CC) + ml) * NN;
    const short* v1p = vsT + ((size_t)(b * CC) + 32 + ml) * NN;

    int nc = w;
    bf16x8 qf_c = bzero8();
    if (!hi) qf_c = *(const bf16x8*)(qbb + (size_t)(nc * 32 + ml) * 8);
    bf16x8 a00_c = *(const bf16x8*)(v0p + nc * 32 + 8 * hi);
    bf16x8 a01_c = *(const bf16x8*)(v0p + nc * 32 + 16 + 8 * hi);
    bf16x8 a10_c = *(const bf16x8*)(v1p + nc * 32 + 8 * hi);
    bf16x8 a11_c = *(const bf16x8*)(v1p + nc * 32 + 16 + 8 * hi);

    for (int i = 0; i < 32; ++i) {
        int ncn = (i < 31) ? nc + 4 : w;
        bf16x8 qf_n = bzero8();
        if (!hi) qf_n = *(const bf16x8*)(qbb + (size_t)(ncn * 32 + ml) * 8);
        bf16x8 a00_n = *(const bf16x8*)(v0p + ncn * 32 + 8 * hi);
        bf16x8 a01_n = *(const bf16x8*)(v0p + ncn * 32 + 16 + 8 * hi);
        bf16x8 a10_n = *(const bf16x8*)(v1p + ncn * 32 + 8 * hi);
        bf16x8 a11_n = *(const bf16x8*)(v1p + ncn * 32 + 16 + 8 * hi);

        f32x16 s = __builtin_amdgcn_mfma_f32_32x32x16_bf16(qf_c, kf, fzero16(), 0, 0, 0);

        unsigned g0 = packbf(__expf(s[0]),  __expf(s[1]));
        unsigned g1 = packbf(__expf(s[2]),  __expf(s[3]));
        unsigned g2 = packbf(__expf(s[4]),  __expf(s[5]));
        unsigned g3 = packbf(__expf(s[6]),  __expf(s[7]));
        unsigned g4 = packbf(__expf(s[8]),  __expf(s[9]));
        unsigned g5 = packbf(__expf(s[10]), __expf(s[11]));
        unsigned g6 = packbf(__expf(s[12]), __expf(s[13]));
        unsigned g7 = packbf(__expf(s[14]), __expf(s[15]));

        unsigned r0 = (unsigned)__shfl_xor((int)(hi ? g0 : g2), 32);
        unsigned r1 = (unsigned)__shfl_xor((int)(hi ? g1 : g3), 32);
        unsigned r2 = (unsigned)__shfl_xor((int)(hi ? g4 : g6), 32);
        unsigned r3 = (unsigned)__shfl_xor((int)(hi ? g5 : g7), 32);

        u32x4 b0u, b1u;
        b0u[0] = hi ? r0 : g0;  b0u[1] = hi ? r1 : g1;
        b0u[2] = hi ? g2 : r0;  b0u[3] = hi ? g3 : r1;
        b1u[0] = hi ? r2 : g4;  b1u[1] = hi ? r3 : g5;
        b1u[2] = hi ? g6 : r2;  b1u[3] = hi ? g7 : r3;
        bf16x8 bf0 = __builtin_bit_cast(bf16x8, b0u);
        bf16x8 bf1 = __builtin_bit_cast(bf16x8, b1u);

        acc0 = __builtin_amdgcn_mfma_f32_32x32x16_bf16(a00_c, bf0, acc0, 0, 0, 0);
        acc0 = __builtin_amdgcn_mfma_f32_32x32x16_bf16(a01_c, bf1, acc0, 0, 0, 0);
        acc1 = __builtin_amdgcn_mfma_f32_32x32x16_bf16(a10_c, bf0, acc1, 0, 0, 0);
        acc1 = __builtin_amdgcn_mfma_f32_32x32x16_bf16(a11_c, bf1, acc1, 0, 0, 0);

        qf_c = qf_n; a00_c = a00_n; a01_c = a01_n; a10_c = a10_n; a11_c = a11_n;
        nc = ncn;
    }

#pragma unroll
    for (int r = 0; r < 16; ++r) {
        int rowr = (r & 3) + 8 * (r >> 2) + 4 * hi;
        red[w][rowr][ml] = acc0[r];
        red[w][rowr + 32][ml] = acc1[r];
    }
    __syncthreads();

    int c = t >> 2;
    int m0 = (t & 3) << 3;
    float4 s0 = *(float4*)&red[0][c][m0];
    float4 s1 = *(float4*)&red[0][c][m0 + 4];
#pragma unroll
    for (int q = 1; q < 4; ++q) {
        float4 a = *(float4*)&red[q][c][m0];
        float4 bq4 = *(float4*)&red[q][c][m0 + 4];
        s0.x += a.x; s0.y += a.y; s0.z += a.z; s0.w += a.w;
        s1.x += bq4.x; s1.y += bq4.y; s1.z += bq4.z; s1.w += bq4.w;
    }
    size_t idx = ((size_t)(b * CC + c)) * NN + mbase + m0;
    float4 xa = *(const float4*)(x + idx);
    float4 xb2 = *(const float4*)(x + idx + 4);
    s0.x += xa.x; s0.y += xa.y; s0.z += xa.z; s0.w += xa.w;
    s1.x += xb2.x; s1.y += xb2.y; s1.z += xb2.z; s1.w += xb2.w;
    *(float4*)(out + idx) = s0;
    *(float4*)(out + idx + 4) = s1;
}

// ---------------------------------------------------------------------------
extern "C" void kernel_launch(void* const* d_in, const int* in_sizes, int n_in,
                              void* d_out, int out_size, void* d_ws, size_t ws_size,
                              hipStream_t stream) {
    const float* x  = (const float*)d_in[0];
    const float* wq = (const float*)d_in[1];
    const float* bq = (const float*)d_in[2];
    const float* wk = (const float*)d_in[3];
    const float* bk = (const float*)d_in[4];
    const float* wv = (const float*)d_in[5];
    const float* bv = (const float*)d_in[6];
    float* out = (float*)d_out;

    char* ws = (char*)d_ws;
    short* qb    = (short*)(ws);                              // 256 KB
    short* kb    = (short*)(ws + (256u << 10));               // 256 KB
    short* vsT   = (short*)(ws + (512u << 10));               // 2 MB
    float* rinv  = (float*)(ws + (512u << 10) + (2u << 20));  // 64 KB
    short* Wp    = (short*)(ws + (640u << 10) + (2u << 20));  // 12 KB
    float* biasp = (float*)(ws + (672u << 10) + (2u << 20));  // 384 B

    w_pack    <<<1,    256, 0, stream>>>(wq, bq, wk, bk, wv, bv, Wp, biasp);
    proj_qk   <<<512,  64,  0, stream>>>(x, Wp, biasp, qb, kb);
    stats_mfma<<<512,  512, 0, stream>>>(qb, kb, rinv);
    proj_v    <<<1024, 64,  0, stream>>>(x, Wp, biasp, rinv, vsT);
    attn_pv   <<<512,  256, 0, stream>>>(qb, kb, vsT, x, out);
}